// Round 13
// baseline (8668.490 us; speedup 1.0000x reference)
//
#include <hip/hip_runtime.h>
#include <cstdint>
#include <cstddef>

#define BATCH 128
#define INF   64
#define OUTF  16
#define SEQ   512
#define FUT   96
#define HID   512
#define G4    2048
#define PROJ  48
#define ECH   4

#define DRG 8
#define DBG 8
#define DUP 64
#define DBP 16

typedef float f32x4 __attribute__((ext_vector_type(4)));

__device__ __forceinline__ float fsigmoid(float x) {
    float e = __builtin_amdgcn_exp2f(-1.4426950408889634f * x);
    return __builtin_amdgcn_rcpf(1.0f + e);
}
__device__ __forceinline__ float ftanh(float x) {
    float e = __builtin_amdgcn_exp2f(2.8853900817779268f * x);
    return 1.0f - 2.0f * __builtin_amdgcn_rcpf(1.0f + e);
}

// LLC-coherent ops for the persistent encoder's cross-WG pipe
__device__ __forceinline__ float gload(const float* p) {
    return __hip_atomic_load(p, __ATOMIC_RELAXED, __HIP_MEMORY_SCOPE_AGENT);
}
__device__ __forceinline__ void gstore(float* p, float v) {
    __hip_atomic_store(p, v, __ATOMIC_RELAXED, __HIP_MEMORY_SCOPE_AGENT);
}

// ---------------- pack W[G4][K] -> WT4[kq][row][4] (dwordx4-loadable) ----------------
__global__ void k_wtrans4(const float* __restrict__ W, float* __restrict__ WT4, int K) {
    int idx = blockIdx.x * 256 + threadIdx.x;       // total G4 * K/4
    int nkq = K / 4;
    if (idx >= G4 * nkq) return;
    int row = idx & (G4 - 1);
    int kq  = idx >> 11;
    f32x4 v;
    v.x = W[(size_t)row * K + kq * 4 + 0];
    v.y = W[(size_t)row * K + kq * 4 + 1];
    v.z = W[(size_t)row * K + kq * 4 + 2];
    v.w = W[(size_t)row * K + kq * 4 + 3];
    *reinterpret_cast<f32x4*>(&WT4[(size_t)idx * 4]) = v;
}

// ---------------- persistent fused encoder: 2 batches per WG ----------------
// grid 128: [0,64) = layer0 pairs, [64,128) = layer1 pairs. Each weight float4
// streamed from L2 feeds 2 independent batch FMA chains (2x intensity).
__global__ __launch_bounds__(512) void k_enc(
    const float* __restrict__ x,
    const float* __restrict__ WT4_0, const float* __restrict__ Whh0,
    const float* __restrict__ bih0, const float* __restrict__ bhh0,
    const float* __restrict__ Whr0,
    const float* __restrict__ WT4_1, const float* __restrict__ Whh1,
    const float* __restrict__ bih1, const float* __restrict__ bhh1,
    const float* __restrict__ Whr1,
    float* __restrict__ H0x, float* __restrict__ H1,
    float* __restrict__ hs, float* __restrict__ cs,
    unsigned* __restrict__ eflags)   // [64][16] per pair
{
    const bool L1w = blockIdx.x >= 64;
    const int pr = blockIdx.x & 63;          // batch pair: batches 2pr, 2pr+1
    const int j = threadIdx.x;
    const int wave = j >> 6, lane = j & 63;
    const float* WT4 = L1w ? WT4_1 : WT4_0;
    const float* Whh = L1w ? Whh1 : Whh0;
    const float* Whr = L1w ? Whr1 : Whr0;
    const float* bih = L1w ? bih1 : bih0;
    const float* bhh = L1w ? bhh1 : bhh0;
    const int K = L1w ? PROJ : INF;

    __shared__ float whr[PROJ][HID + 4];                 // 99 KB
    __shared__ __align__(16) float xs[2][ECH][INF + 4];
    __shared__ __align__(16) float ht_lds[2][HID];
    __shared__ __align__(16) float h_cur[2][PROJ];

    for (int idx = j; idx < PROJ * HID; idx += 512) {
        int p = idx >> 9, jj = idx & 511;
        whr[p][jj] = Whr[(size_t)p * HID + jj];
    }
    float bI = bih[j] + bhh[j];
    float bF = bih[j + HID] + bhh[j + HID];
    float bG = bih[j + 2 * HID] + bhh[j + 2 * HID];
    float bO = bih[j + 3 * HID] + bhh[j + 3 * HID];
    float c2[2] = {0.f, 0.f};
    if (j < 2 * PROJ) h_cur[j / PROJ][j % PROJ] = 0.f;
    __syncthreads();

    const float* w0p = Whh + (size_t)j * PROJ;   // gate rows j, +512, +1024, +1536

    for (int t0 = 0; t0 < SEQ; t0 += ECH) {
        // ---- stage chunk inputs (both batches) ----
        if (!L1w) {
            { // 512 threads = 2b x 64k x 4dt exactly
                int b = j >> 8, rem = j & 255, k = rem >> 2, dt = rem & 3;
                xs[b][dt][k] = x[(size_t)(2 * pr + b) * INF * SEQ + (size_t)k * SEQ + t0 + dt];
            }
        } else {
            if (j == 0) {
                unsigned need = (unsigned)(t0 / ECH) + 1;
                while (__hip_atomic_load(&eflags[pr * 16], __ATOMIC_RELAXED,
                                         __HIP_MEMORY_SCOPE_AGENT) < need)
                    __builtin_amdgcn_s_sleep(2);
            }
            __syncthreads();
            asm volatile("" ::: "memory");
            if (j < 2 * PROJ * ECH) {   // 384 threads
                int b = j / (PROJ * ECH), rem = j % (PROJ * ECH);
                int dt = rem / PROJ, p = rem % PROJ;
                xs[b][dt][p] = gload(&H0x[((size_t)(t0 + dt) * BATCH + 2 * pr + b) * PROJ + p]);
            }
        }
        __syncthreads();

        // ---- fused input-gate GEMM: a[gate][dt][b], WT4 dwordx4 loads ----
        float a0[ECH][2], a1[ECH][2], a2[ECH][2], a3[ECH][2];
        #pragma unroll
        for (int dt = 0; dt < ECH; ++dt)
            #pragma unroll
            for (int b = 0; b < 2; ++b) {
                a0[dt][b] = bI; a1[dt][b] = bF; a2[dt][b] = bG; a3[dt][b] = bO;
            }
        for (int kq = 0; kq < K / 4; ++kq) {
            f32x4 wi = *reinterpret_cast<const f32x4*>(&WT4[((size_t)kq * G4 + j) * 4]);
            f32x4 wf = *reinterpret_cast<const f32x4*>(&WT4[((size_t)kq * G4 + HID + j) * 4]);
            f32x4 wg = *reinterpret_cast<const f32x4*>(&WT4[((size_t)kq * G4 + 2 * HID + j) * 4]);
            f32x4 wo = *reinterpret_cast<const f32x4*>(&WT4[((size_t)kq * G4 + 3 * HID + j) * 4]);
            #pragma unroll
            for (int b = 0; b < 2; ++b)
                #pragma unroll
                for (int dt = 0; dt < ECH; ++dt) {
                    f32x4 xv = *reinterpret_cast<const f32x4*>(&xs[b][dt][kq * 4]);
                    a0[dt][b] += wi.x*xv.x + wi.y*xv.y + wi.z*xv.z + wi.w*xv.w;
                    a1[dt][b] += wf.x*xv.x + wf.y*xv.y + wf.z*xv.z + wf.w*xv.w;
                    a2[dt][b] += wg.x*xv.x + wg.y*xv.y + wg.z*xv.z + wg.w*xv.w;
                    a3[dt][b] += wo.x*xv.x + wo.y*xv.y + wo.z*xv.z + wo.w*xv.w;
                }
        }

        // ---- recurrent steps: Whh streamed once per dt, shared by 2 batches ----
        #pragma unroll
        for (int dt = 0; dt < ECH; ++dt) {
            float ai[2], af[2], ag[2], ao[2];
            #pragma unroll
            for (int b = 0; b < 2; ++b) {
                ai[b] = a0[dt][b]; af[b] = a1[dt][b];
                ag[b] = a2[dt][b]; ao[b] = a3[dt][b];
            }
            #pragma unroll
            for (int k4 = 0; k4 < 12; ++k4) {
                f32x4 wi = *reinterpret_cast<const f32x4*>(w0p + 4 * k4);
                f32x4 wf = *reinterpret_cast<const f32x4*>(w0p + (size_t)HID * PROJ + 4 * k4);
                f32x4 wg = *reinterpret_cast<const f32x4*>(w0p + (size_t)2 * HID * PROJ + 4 * k4);
                f32x4 wo = *reinterpret_cast<const f32x4*>(w0p + (size_t)3 * HID * PROJ + 4 * k4);
                #pragma unroll
                for (int b = 0; b < 2; ++b) {
                    f32x4 h4 = *reinterpret_cast<const f32x4*>(&h_cur[b][4 * k4]);
                    ai[b] += wi.x*h4.x + wi.y*h4.y + wi.z*h4.z + wi.w*h4.w;
                    af[b] += wf.x*h4.x + wf.y*h4.y + wf.z*h4.z + wf.w*h4.w;
                    ag[b] += wg.x*h4.x + wg.y*h4.y + wg.z*h4.z + wg.w*h4.w;
                    ao[b] += wo.x*h4.x + wo.y*h4.y + wo.z*h4.z + wo.w*h4.w;
                }
            }
            #pragma unroll
            for (int b = 0; b < 2; ++b) {
                float si = fsigmoid(ai[b]), sf = fsigmoid(af[b]);
                float so = fsigmoid(ao[b]), tg = ftanh(ag[b]);
                c2[b] = sf * c2[b] + si * tg;
                ht_lds[b][j] = so * ftanh(c2[b]);
            }
            __syncthreads();
            // proj: wave w -> outputs 6w..6w+5, both batches interleaved
            float r0[6], r1[6];
            #pragma unroll
            for (int q = 0; q < 6; ++q) {
                int p = wave * 6 + q;
                float s0 = 0.f, s1 = 0.f;
                #pragma unroll
                for (int m = 0; m < 8; ++m) {
                    float wv = whr[p][lane + 64 * m];
                    s0 += wv * ht_lds[0][lane + 64 * m];
                    s1 += wv * ht_lds[1][lane + 64 * m];
                }
                #pragma unroll
                for (int o = 32; o; o >>= 1) {
                    s0 += __shfl_xor(s0, o, 64);
                    s1 += __shfl_xor(s1, o, 64);
                }
                r0[q] = s0; r1[q] = s1;
            }
            if (lane == 0) {
                int t = t0 + dt;
                #pragma unroll
                for (int q = 0; q < 6; ++q) {
                    int p = wave * 6 + q;
                    h_cur[0][p] = r0[q];
                    h_cur[1][p] = r1[q];
                    if (!L1w) {
                        gstore(&H0x[((size_t)t * BATCH + 2 * pr) * PROJ + p], r0[q]);
                        gstore(&H0x[((size_t)t * BATCH + 2 * pr + 1) * PROJ + p], r1[q]);
                    } else {
                        H1[((size_t)t * BATCH + 2 * pr) * PROJ + p] = r0[q];
                        H1[((size_t)t * BATCH + 2 * pr + 1) * PROJ + p] = r1[q];
                    }
                }
            }
            __syncthreads();
        }
        if (!L1w) {
            asm volatile("s_waitcnt vmcnt(0)" ::: "memory");
            __syncthreads();
            if (j == 0)
                __hip_atomic_store(&eflags[pr * 16], (unsigned)(t0 / ECH) + 1,
                                   __ATOMIC_RELAXED, __HIP_MEMORY_SCOPE_AGENT);
        }
    }
    #pragma unroll
    for (int b = 0; b < 2; ++b)
        cs[((size_t)(L1w ? BATCH : 0) + 2 * pr + b) * HID + j] = c2[b];
    if (j < 2 * PROJ) {
        int b = j / PROJ, p = j % PROJ;
        hs[((size_t)(L1w ? BATCH : 0) + 2 * pr + b) * PROJ + p] = h_cur[b][p];
    }
}

// ---------------- decoder phase A: spill-free (4 thr/row x 2 passes) ----------------
__global__ __launch_bounds__(512) void k_decA(
    const float* __restrict__ xdec,
    const float* __restrict__ Wih0, const float* __restrict__ Whh0,
    const float* __restrict__ bih0, const float* __restrict__ bhh0,
    const float* __restrict__ Whr0,
    const float* __restrict__ hs, float* __restrict__ cs0,
    const float* __restrict__ xin,
    const float* __restrict__ PPa_r, float* __restrict__ PPa_w,
    const float* __restrict__ PPb_r, float* __restrict__ PRED, int t)
{
    const int bg = blockIdx.x & 7, rg = blockIdx.x >> 3;
    const int tid = threadIdx.x;
    const int kq = tid & 3, rhalf = tid >> 2;
    const int u2 = tid >> 3, b2 = tid & 7;
    const int uglob = rg * DUP + u2;
    const int w = tid >> 6, lane = tid & 63;
    const size_t PSTR = (size_t)BATCH * PROJ;

    __shared__ __align__(16) float inp0[DBP][120];
    __shared__ float xch[4][DUP][17];
    __shared__ float htl[DBP][68];
    __shared__ float wslT0[DUP][52];

    for (int i = tid; i < PROJ * DUP; i += 512) {
        int p = i >> 6, uu = i & 63;
        wslT0[uu][p] = Whr0[(size_t)p * HID + rg * DUP + uu];
    }
    float bs0[4];
    #pragma unroll
    for (int gg = 0; gg < 4; ++gg)
        bs0[gg] = bih0[gg * HID + uglob] + bhh0[gg * HID + uglob];
    float c0[2];
    #pragma unroll
    for (int hh = 0; hh < 2; ++hh)
        c0[hh] = cs0[(size_t)(bg * DBP + b2 + 8 * hh) * HID + uglob];

    if (t == 0) {
        for (int i = tid; i < DBP * PROJ; i += 512) {
            int b = i / PROJ, p = i % PROJ;
            int bglob = bg * DBP + b;
            inp0[b][p]      = hs[(size_t)bglob * PROJ + p];
            inp0[b][48 + p] = xin[(size_t)bglob * INF * SEQ + (size_t)p * SEQ + (SEQ - 1)];
        }
        if (tid < DBP * OUTF) {
            int b = tid >> 4, f = tid & 15;
            inp0[b][96 + f] = xdec[(size_t)(bg * DBP + b) * (OUTF * FUT) + (size_t)f * FUT];
        }
    } else {
        if (tid < 192) {
            int b = tid / 12, p = (tid % 12) * 4;
            int bglob = bg * DBP + b;
            f32x4 s = {0.f, 0.f, 0.f, 0.f};
            #pragma unroll
            for (int rr = 0; rr < DRG; ++rr)
                s += *reinterpret_cast<const f32x4*>(&PPa_r[(size_t)rr * PSTR + (size_t)bglob * PROJ + p]);
            *reinterpret_cast<f32x4*>(&inp0[b][p]) = s;
        } else if (tid < 384) {
            int idx = tid - 192;
            int b = idx / 12, p = (idx % 12) * 4;
            int bglob = bg * DBP + b;
            f32x4 s = {0.f, 0.f, 0.f, 0.f};
            #pragma unroll
            for (int rr = 0; rr < DRG; ++rr)
                s += *reinterpret_cast<const f32x4*>(&PPb_r[(size_t)rr * PSTR + (size_t)bglob * PROJ + p]);
            *reinterpret_cast<f32x4*>(&inp0[b][48 + p]) = s;
            if (rg == 0)
                *reinterpret_cast<f32x4*>(&PRED[((size_t)(t - 1) * BATCH + bglob) * PROJ + p]) = s;
        } else {
            #pragma unroll
            for (int rep = 0; rep < 2; ++rep) {
                int i2 = (tid - 384) + rep * 128;
                int b = i2 >> 4, f = i2 & 15;
                inp0[b][96 + f] = xdec[(size_t)(bg * DBP + b) * (OUTF * FUT) + (size_t)f * FUT + t];
            }
        }
    }
    __syncthreads();

    #pragma unroll
    for (int p = 0; p < 2; ++p) {
        int rid = p * 128 + rhalf;
        int g = rid >> 6, u = rid & 63;
        int grow = g * HID + rg * DUP + u;
        float wv[28];
        #pragma unroll
        for (int kk = 0; kk < 28; ++kk) {
            int k = kq * 28 + kk;
            wv[kk] = (k < 48) ? Whh0[(size_t)grow * 48 + k]
                              : Wih0[(size_t)grow * 64 + (k - 48)];
        }
        float acc[DBP];
        #pragma unroll
        for (int b = 0; b < DBP; ++b) acc[b] = 0.f;
        const float* srcA = &inp0[0][0] + kq * 28;
        #pragma unroll
        for (int i4 = 0; i4 < 7; ++i4) {
            float w0 = wv[i4*4], w1 = wv[i4*4+1], w2 = wv[i4*4+2], w3 = wv[i4*4+3];
            #pragma unroll
            for (int b = 0; b < DBP; ++b) {
                float4 xv = *reinterpret_cast<const float4*>(&srcA[b * 120 + i4 * 4]);
                acc[b] += w0*xv.x + w1*xv.y + w2*xv.z + w3*xv.w;
            }
        }
        #pragma unroll
        for (int b = 0; b < DBP; ++b) {
            acc[b] += __shfl_xor(acc[b], 1, 64);
            acc[b] += __shfl_xor(acc[b], 2, 64);
        }
        if (kq == 0) {
            #pragma unroll
            for (int b = 0; b < DBP; ++b) xch[g][u][b] = acc[b];
        }
    }
    __syncthreads();
    #pragma unroll
    for (int hh = 0; hh < 2; ++hh) {
        int b = b2 + 8 * hh;
        float gi = xch[0][u2][b] + bs0[0];
        float gf = xch[1][u2][b] + bs0[1];
        float gc = xch[2][u2][b] + bs0[2];
        float go = xch[3][u2][b] + bs0[3];
        float si = fsigmoid(gi), sf = fsigmoid(gf), so = fsigmoid(go), tg = ftanh(gc);
        c0[hh] = sf * c0[hh] + si * tg;
        htl[b][u2] = so * ftanh(c0[hh]);
        cs0[(size_t)(bg * DBP + b) * HID + uglob] = c0[hh];
    }
    __syncthreads();
    if (lane < PROJ) {
        #pragma unroll
        for (int bb = 0; bb < 2; ++bb) {
            int b = 2 * w + bb;
            float s = 0.f;
            #pragma unroll
            for (int u4 = 0; u4 < 16; ++u4) {
                float4 hv = *reinterpret_cast<const float4*>(&htl[b][u4 * 4]);
                s += wslT0[u4*4+0][lane]*hv.x + wslT0[u4*4+1][lane]*hv.y
                   + wslT0[u4*4+2][lane]*hv.z + wslT0[u4*4+3][lane]*hv.w;
            }
            PPa_w[(size_t)rg * PSTR + (size_t)(bg * DBP + b) * PROJ + lane] = s;
        }
    }
}

// ---------------- decoder phase B: spill-free ----------------
__global__ __launch_bounds__(512) void k_decB(
    const float* __restrict__ Wih1, const float* __restrict__ Whh1,
    const float* __restrict__ bih1, const float* __restrict__ bhh1,
    const float* __restrict__ Whr1,
    const float* __restrict__ hs, float* __restrict__ cs1,
    const float* __restrict__ PPa_r, const float* __restrict__ PPb_r,
    float* __restrict__ PPb_w, int t)
{
    const int bg = blockIdx.x & 7, rg = blockIdx.x >> 3;
    const int tid = threadIdx.x;
    const int kq = tid & 3, rhalf = tid >> 2;
    const int u2 = tid >> 3, b2 = tid & 7;
    const int uglob = rg * DUP + u2;
    const int w = tid >> 6, lane = tid & 63;
    const size_t PSTR = (size_t)BATCH * PROJ;

    __shared__ __align__(16) float h0n[DBP][52];
    __shared__ __align__(16) float h1b[DBP][52];
    __shared__ float xch[4][DUP][17];
    __shared__ float htl[DBP][68];
    __shared__ float wslT1[DUP][52];

    for (int i = tid; i < PROJ * DUP; i += 512) {
        int p = i >> 6, uu = i & 63;
        wslT1[uu][p] = Whr1[(size_t)p * HID + rg * DUP + uu];
    }
    float bs1[4];
    #pragma unroll
    for (int gg = 0; gg < 4; ++gg)
        bs1[gg] = bih1[gg * HID + uglob] + bhh1[gg * HID + uglob];
    float c1[2];
    #pragma unroll
    for (int hh = 0; hh < 2; ++hh)
        c1[hh] = cs1[(size_t)(bg * DBP + b2 + 8 * hh) * HID + uglob];

    if (tid < 192) {
        int b = tid / 12, p = (tid % 12) * 4;
        int bglob = bg * DBP + b;
        f32x4 s = {0.f, 0.f, 0.f, 0.f};
        #pragma unroll
        for (int rr = 0; rr < DRG; ++rr)
            s += *reinterpret_cast<const f32x4*>(&PPa_r[(size_t)rr * PSTR + (size_t)bglob * PROJ + p]);
        *reinterpret_cast<f32x4*>(&h0n[b][p]) = s;
    } else if (tid < 384) {
        int idx = tid - 192;
        int b = idx / 12, p = (idx % 12) * 4;
        int bglob = bg * DBP + b;
        if (t == 0) {
            f32x4 s = *reinterpret_cast<const f32x4*>(&hs[(size_t)(BATCH + bglob) * PROJ + p]);
            *reinterpret_cast<f32x4*>(&h1b[b][p]) = s;
        } else {
            f32x4 s = {0.f, 0.f, 0.f, 0.f};
            #pragma unroll
            for (int rr = 0; rr < DRG; ++rr)
                s += *reinterpret_cast<const f32x4*>(&PPb_r[(size_t)rr * PSTR + (size_t)bglob * PROJ + p]);
            *reinterpret_cast<f32x4*>(&h1b[b][p]) = s;
        }
    }
    __syncthreads();

    #pragma unroll
    for (int p = 0; p < 2; ++p) {
        int rid = p * 128 + rhalf;
        int g = rid >> 6, u = rid & 63;
        int grow = g * HID + rg * DUP + u;
        float wv[24];
        #pragma unroll
        for (int kk = 0; kk < 24; ++kk) {
            int k = kq * 24 + kk;
            wv[kk] = (k < 48) ? Whh1[(size_t)grow * 48 + k]
                              : Wih1[(size_t)grow * 48 + (k - 48)];
        }
        const float* srcB = (kq < 2) ? (&h1b[0][0] + kq * 24)
                                     : (&h0n[0][0] + (kq - 2) * 24);
        float acc[DBP];
        #pragma unroll
        for (int b = 0; b < DBP; ++b) acc[b] = 0.f;
        #pragma unroll
        for (int i4 = 0; i4 < 6; ++i4) {
            float w0 = wv[i4*4], w1 = wv[i4*4+1], w2 = wv[i4*4+2], w3 = wv[i4*4+3];
            #pragma unroll
            for (int b = 0; b < DBP; ++b) {
                float4 xv = *reinterpret_cast<const float4*>(&srcB[b * 52 + i4 * 4]);
                acc[b] += w0*xv.x + w1*xv.y + w2*xv.z + w3*xv.w;
            }
        }
        #pragma unroll
        for (int b = 0; b < DBP; ++b) {
            acc[b] += __shfl_xor(acc[b], 1, 64);
            acc[b] += __shfl_xor(acc[b], 2, 64);
        }
        if (kq == 0) {
            #pragma unroll
            for (int b = 0; b < DBP; ++b) xch[g][u][b] = acc[b];
        }
    }
    __syncthreads();
    #pragma unroll
    for (int hh = 0; hh < 2; ++hh) {
        int b = b2 + 8 * hh;
        float gi = xch[0][u2][b] + bs1[0];
        float gf = xch[1][u2][b] + bs1[1];
        float gc = xch[2][u2][b] + bs1[2];
        float go = xch[3][u2][b] + bs1[3];
        float si = fsigmoid(gi), sf = fsigmoid(gf), so = fsigmoid(go), tg = ftanh(gc);
        c1[hh] = sf * c1[hh] + si * tg;
        htl[b][u2] = so * ftanh(c1[hh]);
        cs1[(size_t)(bg * DBP + b) * HID + uglob] = c1[hh];
    }
    __syncthreads();
    if (lane < PROJ) {
        #pragma unroll
        for (int bb = 0; bb < 2; ++bb) {
            int b = 2 * w + bb;
            float s = 0.f;
            #pragma unroll
            for (int u4 = 0; u4 < 16; ++u4) {
                float4 hv = *reinterpret_cast<const float4*>(&htl[b][u4 * 4]);
                s += wslT1[u4*4+0][lane]*hv.x + wslT1[u4*4+1][lane]*hv.y
                   + wslT1[u4*4+2][lane]*hv.z + wslT1[u4*4+3][lane]*hv.w;
            }
            PPb_w[(size_t)rg * PSTR + (size_t)(bg * DBP + b) * PROJ + lane] = s;
        }
    }
}

// ---------------- epilogue: PRED[FUT-1] ----------------
__global__ void k_predlast(const float* __restrict__ PPb_r, float* __restrict__ PRED) {
    int b = blockIdx.x;
    int p = threadIdx.x;
    if (p < PROJ) {
        const size_t PSTR = (size_t)BATCH * PROJ;
        float s = 0.f;
        #pragma unroll
        for (int rr = 0; rr < DRG; ++rr)
            s += PPb_r[(size_t)rr * PSTR + (size_t)b * PROJ + p];
        PRED[((size_t)(FUT - 1) * BATCH + b) * PROJ + p] = s;
    }
}

// ---------------- basis contractions ----------------
__global__ void k_final(const float* __restrict__ theta, const float* __restrict__ H1,
                        const float* __restrict__ PRED, float* __restrict__ out)
{
    int b = blockIdx.x;
    __shared__ float th[2 * PROJ];
    if (threadIdx.x < 2 * PROJ) th[threadIdx.x] = theta[(size_t)b * 2 * PROJ + threadIdx.x];
    __syncthreads();
    for (int t = threadIdx.x; t < SEQ; t += 256) {
        float s = 0.f;
        #pragma unroll
        for (int p = 0; p < PROJ; ++p) s += th[PROJ + p] * H1[((size_t)t * BATCH + b) * PROJ + p];
        out[(size_t)b * SEQ + t] = s;
    }
    for (int t = threadIdx.x; t < FUT; t += 256) {
        float s = 0.f;
        #pragma unroll
        for (int p = 0; p < PROJ; ++p) s += th[p] * PRED[((size_t)t * BATCH + b) * PROJ + p];
        out[(size_t)BATCH * SEQ + (size_t)b * FUT + t] = s;
    }
}

extern "C" void kernel_launch(void* const* d_in, const int* in_sizes, int n_in,
                              void* d_out, int out_size, void* d_ws, size_t ws_size,
                              hipStream_t stream)
{
    (void)in_sizes; (void)n_in; (void)out_size; (void)ws_size;
    const float* theta = (const float*)d_in[0];
    const float* xin   = (const float*)d_in[1];
    const float* xdec  = (const float*)d_in[2];
    const float* eW0i = (const float*)d_in[3];
    const float* eW0h = (const float*)d_in[4];
    const float* eb0i = (const float*)d_in[5];
    const float* eb0h = (const float*)d_in[6];
    const float* eW0r = (const float*)d_in[7];
    const float* eW1i = (const float*)d_in[8];
    const float* eW1h = (const float*)d_in[9];
    const float* eb1i = (const float*)d_in[10];
    const float* eb1h = (const float*)d_in[11];
    const float* eW1r = (const float*)d_in[12];
    const float* dW0i = (const float*)d_in[13];
    const float* dW0h = (const float*)d_in[14];
    const float* db0i = (const float*)d_in[15];
    const float* db0h = (const float*)d_in[16];
    const float* dW0r = (const float*)d_in[17];
    const float* dW1i = (const float*)d_in[18];
    const float* dW1h = (const float*)d_in[19];
    const float* db1i = (const float*)d_in[20];
    const float* db1h = (const float*)d_in[21];
    const float* dW1r = (const float*)d_in[22];

    float* ws = (float*)d_ws;
    size_t off = 0;
    float* H0x  = ws + off; off += (size_t)SEQ * BATCH * PROJ;
    float* H1   = ws + off; off += (size_t)SEQ * BATCH * PROJ;
    float* PRED = ws + off; off += (size_t)FUT * BATCH * PROJ;
    float* hs   = ws + off; off += (size_t)2 * BATCH * PROJ;
    float* cs   = ws + off; off += (size_t)2 * BATCH * HID;
    float* WT4_0 = ws + off; off += (size_t)INF * G4;
    float* WT4_1 = ws + off; off += (size_t)PROJ * G4;
    const size_t DPP = (size_t)DRG * BATCH * PROJ;
    float* PPa  = ws + off; off += 2 * DPP;
    float* PPb  = ws + off; off += 2 * DPP;
    off = (off + 63) & ~(size_t)63;
    unsigned* eflags = (unsigned*)(ws + off); off += 64 * 16;

    float* cs0 = cs;
    float* cs1 = cs + (size_t)BATCH * HID;

    hipMemsetAsync(eflags, 0, 64 * 16 * sizeof(unsigned), stream);
    k_wtrans4<<<(G4 * (INF / 4) + 255) / 256, 256, 0, stream>>>(eW0i, WT4_0, INF);
    k_wtrans4<<<(G4 * (PROJ / 4) + 255) / 256, 256, 0, stream>>>(eW1i, WT4_1, PROJ);
    k_enc<<<128, 512, 0, stream>>>(xin,
                                   WT4_0, eW0h, eb0i, eb0h, eW0r,
                                   WT4_1, eW1h, eb1i, eb1h, eW1r,
                                   H0x, H1, hs, cs, eflags);

    for (int t = 0; t < FUT; ++t) {
        const float* ppaR = PPa + (size_t)((t - 1) & 1) * DPP;
        float*       ppaW = PPa + (size_t)(t & 1) * DPP;
        const float* ppbR = PPb + (size_t)((t - 1) & 1) * DPP;
        float*       ppbW = PPb + (size_t)(t & 1) * DPP;
        k_decA<<<DRG * DBG, 512, 0, stream>>>(xdec, dW0i, dW0h, db0i, db0h, dW0r,
                                              hs, cs0, xin, ppaR, ppaW, ppbR, PRED, t);
        k_decB<<<DRG * DBG, 512, 0, stream>>>(dW1i, dW1h, db1i, db1h, dW1r,
                                              hs, cs1, ppaW, ppbR, ppbW, t);
    }
    k_predlast<<<BATCH, 64, 0, stream>>>(PPb + (size_t)((FUT - 1) & 1) * DPP, PRED);
    k_final<<<BATCH, 256, 0, stream>>>(theta, H1, PRED, (float*)d_out);
}

// Round 14
// 4996.004 us; speedup vs baseline: 1.7351x; 1.7351x over previous
//
#include <hip/hip_runtime.h>
#include <cstdint>
#include <cstddef>

#define BATCH 128
#define INF   64
#define OUTF  16
#define SEQ   512
#define FUT   96
#define HID   512
#define G4    2048
#define PROJ  48
#define ECH   4

#define DRG 8
#define DBG 8
#define DUP 64
#define DBP 16

typedef float f32x4 __attribute__((ext_vector_type(4)));

__device__ __forceinline__ float fsigmoid(float x) {
    float e = __builtin_amdgcn_exp2f(-1.4426950408889634f * x);
    return __builtin_amdgcn_rcpf(1.0f + e);
}
__device__ __forceinline__ float ftanh(float x) {
    float e = __builtin_amdgcn_exp2f(2.8853900817779268f * x);
    return 1.0f - 2.0f * __builtin_amdgcn_rcpf(1.0f + e);
}

// LLC-coherent scalar ops (cross-WG traffic)
__device__ __forceinline__ float gload(const float* p) {
    return __hip_atomic_load(p, __ATOMIC_RELAXED, __HIP_MEMORY_SCOPE_AGENT);
}
__device__ __forceinline__ void gstore(float* p, float v) {
    __hip_atomic_store(p, v, __ATOMIC_RELAXED, __HIP_MEMORY_SCOPE_AGENT);
}

// coherent vector gather: sum of 8 partials at p + rr*stride, fixed tree order.
__device__ __forceinline__ f32x4 gsum8(const float* p, size_t stride) {
    f32x4 a0, a1, a2, a3, a4, a5, a6, a7;
    asm volatile(
        "global_load_dwordx4 %0, %8, off sc0 sc1\n\t"
        "global_load_dwordx4 %1, %9, off sc0 sc1\n\t"
        "global_load_dwordx4 %2, %10, off sc0 sc1\n\t"
        "global_load_dwordx4 %3, %11, off sc0 sc1\n\t"
        "global_load_dwordx4 %4, %12, off sc0 sc1\n\t"
        "global_load_dwordx4 %5, %13, off sc0 sc1\n\t"
        "global_load_dwordx4 %6, %14, off sc0 sc1\n\t"
        "global_load_dwordx4 %7, %15, off sc0 sc1\n\t"
        "s_waitcnt vmcnt(0)"
        : "=&v"(a0), "=&v"(a1), "=&v"(a2), "=&v"(a3),
          "=&v"(a4), "=&v"(a5), "=&v"(a6), "=&v"(a7)
        : "v"(p), "v"(p + stride), "v"(p + 2 * stride), "v"(p + 3 * stride),
          "v"(p + 4 * stride), "v"(p + 5 * stride), "v"(p + 6 * stride),
          "v"(p + 7 * stride)
        : "memory");
    return ((a0 + a1) + (a2 + a3)) + ((a4 + a5) + (a6 + a7));
}

// chain barrier among DRG WGs: counter add by tid0, poll with backoff.
__device__ __forceinline__ void bsync(unsigned* ctr, unsigned target, int tid) {
    asm volatile("s_waitcnt vmcnt(0)" ::: "memory");
    __syncthreads();
    if (tid == 0) {
        __hip_atomic_fetch_add(ctr, 1u, __ATOMIC_RELAXED, __HIP_MEMORY_SCOPE_AGENT);
        while (__hip_atomic_load(ctr, __ATOMIC_RELAXED, __HIP_MEMORY_SCOPE_AGENT) < target)
            __builtin_amdgcn_s_sleep(2);
    }
    __syncthreads();
    asm volatile("" ::: "memory");
}

// ---------------- guarded transpose W[R][C] -> WT[C][R] ----------------
__global__ void k_wtrans(const float* __restrict__ W, float* __restrict__ WT,
                         int R, int C) {
    __shared__ float tile[32][33];
    int r0 = blockIdx.x * 32, c0 = blockIdx.y * 32;
    int tx = threadIdx.x, ty = threadIdx.y;
    #pragma unroll
    for (int i = 0; i < 4; ++i) {
        int r = r0 + ty + 8 * i;
        if (r < R && c0 + tx < C) tile[ty + 8 * i][tx] = W[(size_t)r * C + c0 + tx];
    }
    __syncthreads();
    #pragma unroll
    for (int i = 0; i < 4; ++i) {
        int c = c0 + ty + 8 * i;
        if (c < C && r0 + tx < R) WT[(size_t)c * R + r0 + tx] = tile[tx][ty + 8 * i];
    }
}

// ---------------- persistent fused encoder (R11-exact, 3.12ms known-good) ----------------
__global__ __launch_bounds__(512) void k_enc(
    const float* __restrict__ x,
    const float* __restrict__ WT0, const float* __restrict__ Whh0,
    const float* __restrict__ bih0, const float* __restrict__ bhh0,
    const float* __restrict__ Whr0,
    const float* __restrict__ WT1, const float* __restrict__ Whh1,
    const float* __restrict__ bih1, const float* __restrict__ bhh1,
    const float* __restrict__ Whr1,
    float* __restrict__ H0x, float* __restrict__ H1,
    float* __restrict__ hs, float* __restrict__ cs,
    unsigned* __restrict__ eflags)
{
    const bool L1w = blockIdx.x >= BATCH;
    const int b = L1w ? blockIdx.x - BATCH : blockIdx.x;
    const int j = threadIdx.x;
    const int wave = j >> 6, lane = j & 63;
    const float* WT  = L1w ? WT1 : WT0;
    const float* Whh = L1w ? Whh1 : Whh0;
    const float* Whr = L1w ? Whr1 : Whr0;
    const float* bih = L1w ? bih1 : bih0;
    const float* bhh = L1w ? bhh1 : bhh0;
    const int K = L1w ? PROJ : INF;

    __shared__ float whr[PROJ][HID + 4];
    __shared__ __align__(16) float xs[ECH][INF + 4];
    __shared__ __align__(16) float ht_lds[HID];
    __shared__ __align__(16) float h_cur[PROJ];

    float wI[PROJ], wF[PROJ], wG[PROJ], wO[PROJ];
    #pragma unroll
    for (int k4 = 0; k4 < 12; ++k4) {
        float4 vi = *reinterpret_cast<const float4*>(&Whh[(size_t)j * PROJ + 4 * k4]);
        float4 vf = *reinterpret_cast<const float4*>(&Whh[(size_t)(j + HID) * PROJ + 4 * k4]);
        float4 vg = *reinterpret_cast<const float4*>(&Whh[(size_t)(j + 2 * HID) * PROJ + 4 * k4]);
        float4 vo = *reinterpret_cast<const float4*>(&Whh[(size_t)(j + 3 * HID) * PROJ + 4 * k4]);
        wI[4*k4+0]=vi.x; wI[4*k4+1]=vi.y; wI[4*k4+2]=vi.z; wI[4*k4+3]=vi.w;
        wF[4*k4+0]=vf.x; wF[4*k4+1]=vf.y; wF[4*k4+2]=vf.z; wF[4*k4+3]=vf.w;
        wG[4*k4+0]=vg.x; wG[4*k4+1]=vg.y; wG[4*k4+2]=vg.z; wG[4*k4+3]=vg.w;
        wO[4*k4+0]=vo.x; wO[4*k4+1]=vo.y; wO[4*k4+2]=vo.z; wO[4*k4+3]=vo.w;
    }
    for (int idx = j; idx < PROJ * HID; idx += 512) {
        int p = idx >> 9, jj = idx & 511;
        whr[p][jj] = Whr[(size_t)p * HID + jj];
    }
    float bI = bih[j] + bhh[j];
    float bF = bih[j + HID] + bhh[j + HID];
    float bG = bih[j + 2 * HID] + bhh[j + 2 * HID];
    float bO = bih[j + 3 * HID] + bhh[j + 3 * HID];
    float c = 0.f;
    if (j < PROJ) h_cur[j] = 0.f;
    __syncthreads();

    for (int t0 = 0; t0 < SEQ; t0 += ECH) {
        if (!L1w) {
            if (j < INF * ECH) {
                int k = j >> 2, dt = j & 3;
                xs[dt][k] = x[(size_t)b * INF * SEQ + (size_t)k * SEQ + t0 + dt];
            }
        } else {
            if (j == 0) {
                unsigned need = (unsigned)(t0 / ECH) + 1;
                while (__hip_atomic_load(&eflags[b * 16], __ATOMIC_RELAXED,
                                         __HIP_MEMORY_SCOPE_AGENT) < need)
                    __builtin_amdgcn_s_sleep(2);
            }
            __syncthreads();
            asm volatile("" ::: "memory");
            if (j < PROJ * ECH) {
                int dt = j / PROJ, p = j % PROJ;
                xs[dt][p] = gload(&H0x[((size_t)(t0 + dt) * BATCH + b) * PROJ + p]);
            }
        }
        __syncthreads();

        float a0[ECH], a1[ECH], a2[ECH], a3[ECH];
        #pragma unroll
        for (int dt = 0; dt < ECH; ++dt) { a0[dt] = bI; a1[dt] = bF; }
        for (int kq = 0; kq < K / 4; ++kq) {
            float wi0 = WT[(size_t)(kq*4+0) * G4 + j];
            float wi1 = WT[(size_t)(kq*4+1) * G4 + j];
            float wi2 = WT[(size_t)(kq*4+2) * G4 + j];
            float wi3 = WT[(size_t)(kq*4+3) * G4 + j];
            float wf0 = WT[(size_t)(kq*4+0) * G4 + HID + j];
            float wf1 = WT[(size_t)(kq*4+1) * G4 + HID + j];
            float wf2 = WT[(size_t)(kq*4+2) * G4 + HID + j];
            float wf3 = WT[(size_t)(kq*4+3) * G4 + HID + j];
            #pragma unroll
            for (int dt = 0; dt < ECH; ++dt) {
                float4 xv = *reinterpret_cast<const float4*>(&xs[dt][kq * 4]);
                a0[dt] += wi0*xv.x + wi1*xv.y + wi2*xv.z + wi3*xv.w;
                a1[dt] += wf0*xv.x + wf1*xv.y + wf2*xv.z + wf3*xv.w;
            }
        }
        #pragma unroll
        for (int dt = 0; dt < ECH; ++dt) { a2[dt] = bG; a3[dt] = bO; }
        for (int kq = 0; kq < K / 4; ++kq) {
            float wg0 = WT[(size_t)(kq*4+0) * G4 + 2 * HID + j];
            float wg1 = WT[(size_t)(kq*4+1) * G4 + 2 * HID + j];
            float wg2 = WT[(size_t)(kq*4+2) * G4 + 2 * HID + j];
            float wg3 = WT[(size_t)(kq*4+3) * G4 + 2 * HID + j];
            float wo0 = WT[(size_t)(kq*4+0) * G4 + 3 * HID + j];
            float wo1 = WT[(size_t)(kq*4+1) * G4 + 3 * HID + j];
            float wo2 = WT[(size_t)(kq*4+2) * G4 + 3 * HID + j];
            float wo3 = WT[(size_t)(kq*4+3) * G4 + 3 * HID + j];
            #pragma unroll
            for (int dt = 0; dt < ECH; ++dt) {
                float4 xv = *reinterpret_cast<const float4*>(&xs[dt][kq * 4]);
                a2[dt] += wg0*xv.x + wg1*xv.y + wg2*xv.z + wg3*xv.w;
                a3[dt] += wo0*xv.x + wo1*xv.y + wo2*xv.z + wo3*xv.w;
            }
        }

        #pragma unroll
        for (int dt = 0; dt < ECH; ++dt) {
            float ai = a0[dt], af = a1[dt], ag = a2[dt], ao = a3[dt];
            #pragma unroll
            for (int k4 = 0; k4 < 12; ++k4) {
                float4 h4 = *reinterpret_cast<const float4*>(&h_cur[4 * k4]);
                ai += wI[4*k4+0]*h4.x + wI[4*k4+1]*h4.y + wI[4*k4+2]*h4.z + wI[4*k4+3]*h4.w;
                af += wF[4*k4+0]*h4.x + wF[4*k4+1]*h4.y + wF[4*k4+2]*h4.z + wF[4*k4+3]*h4.w;
                ag += wG[4*k4+0]*h4.x + wG[4*k4+1]*h4.y + wG[4*k4+2]*h4.z + wG[4*k4+3]*h4.w;
                ao += wO[4*k4+0]*h4.x + wO[4*k4+1]*h4.y + wO[4*k4+2]*h4.z + wO[4*k4+3]*h4.w;
            }
            float si = fsigmoid(ai), sf = fsigmoid(af), so = fsigmoid(ao), tg = ftanh(ag);
            c = sf * c + si * tg;
            ht_lds[j] = so * ftanh(c);
            __syncthreads();
            float rq[6];
            #pragma unroll
            for (int q = 0; q < 6; ++q) {
                int p = wave * 6 + q;
                float s = 0.f;
                #pragma unroll
                for (int m = 0; m < 8; ++m)
                    s += whr[p][lane + 64 * m] * ht_lds[lane + 64 * m];
                #pragma unroll
                for (int o = 32; o; o >>= 1) s += __shfl_xor(s, o, 64);
                rq[q] = s;
            }
            if (lane == 0) {
                int t = t0 + dt;
                #pragma unroll
                for (int q = 0; q < 6; ++q) {
                    int p = wave * 6 + q;
                    float v = rq[q];
                    h_cur[p] = v;
                    if (!L1w) gstore(&H0x[((size_t)t * BATCH + b) * PROJ + p], v);
                    else      H1[((size_t)t * BATCH + b) * PROJ + p] = v;
                }
            }
            __syncthreads();
        }
        if (!L1w) {
            asm volatile("s_waitcnt vmcnt(0)" ::: "memory");
            __syncthreads();
            if (j == 0)
                __hip_atomic_store(&eflags[b * 16], (unsigned)(t0 / ECH) + 1,
                                   __ATOMIC_RELAXED, __HIP_MEMORY_SCOPE_AGENT);
        }
    }
    cs[((size_t)(L1w ? BATCH : 0) + b) * HID + j] = c;
    if (j < PROJ) hs[((size_t)(L1w ? BATCH : 0) + b) * PROJ + j] = h_cur[j];
}

// ---------------- persistent spill-free decoder: 64 WGs, 2 syncs/step ----------------
__global__ __launch_bounds__(512) void k_decP(
    const float* __restrict__ xdec,
    const float* __restrict__ Wih0, const float* __restrict__ Whh0,
    const float* __restrict__ bih0, const float* __restrict__ bhh0,
    const float* __restrict__ Whr0,
    const float* __restrict__ Wih1, const float* __restrict__ Whh1,
    const float* __restrict__ bih1, const float* __restrict__ bhh1,
    const float* __restrict__ Whr1,
    const float* __restrict__ hs, const float* __restrict__ cs,
    const float* __restrict__ xin,
    float* __restrict__ PPa,    // [2][DRG][BATCH][48]
    float* __restrict__ PPb,    // [2][DRG][BATCH][48]
    float* __restrict__ PRED,   // [FUT][BATCH][48]
    unsigned* __restrict__ bar) // [DBG][64]
{
    const int bg = blockIdx.x & 7, rg = blockIdx.x >> 3;
    const int tid = threadIdx.x;
    const int kq = tid & 3, rhalf = tid >> 2;
    const int u2 = tid >> 3, b2 = tid & 7;
    const int uglob = rg * DUP + u2;
    const int w = tid >> 6, lane = tid & 63;
    const size_t PSTR = (size_t)BATCH * PROJ;
    const size_t DPP  = (size_t)DRG * PSTR;

    __shared__ __align__(16) float inp0[DBP][120];
    __shared__ __align__(16) float h1b[DBP][52];
    __shared__ __align__(16) float h0n[DBP][52];
    __shared__ float xch[4][DUP][17];
    __shared__ float htl[DBP][68];
    __shared__ float wslT0[DUP][52];
    __shared__ float wslT1[DUP][52];

    for (int i = tid; i < PROJ * DUP; i += 512) {
        int p = i >> 6, uu = i & 63;
        wslT0[uu][p] = Whr0[(size_t)p * HID + rg * DUP + uu];
        wslT1[uu][p] = Whr1[(size_t)p * HID + rg * DUP + uu];
    }
    float bs0[4], bs1[4];
    #pragma unroll
    for (int gg = 0; gg < 4; ++gg) {
        bs0[gg] = bih0[gg * HID + uglob] + bhh0[gg * HID + uglob];
        bs1[gg] = bih1[gg * HID + uglob] + bhh1[gg * HID + uglob];
    }
    float c0[2], c1[2];
    #pragma unroll
    for (int hh = 0; hh < 2; ++hh) {
        int bglob = bg * DBP + b2 + 8 * hh;
        c0[hh] = cs[(size_t)bglob * HID + uglob];
        c1[hh] = cs[(size_t)(BATCH + bglob) * HID + uglob];
    }
    __syncthreads();

    unsigned* ctr = bar + bg * 64;
    unsigned phase = 0;

    for (int t = 0; t < FUT; ++t) {
        const float* ppaR = PPa + (size_t)((t - 1) & 1) * DPP;
        float*       ppaW = PPa + (size_t)(t & 1) * DPP;
        const float* ppbR = PPb + (size_t)((t - 1) & 1) * DPP;
        float*       ppbW = PPb + (size_t)(t & 1) * DPP;

        // ================= PHASE A: stage + L0 + proj0 =================
        if (t == 0) {
            for (int i = tid; i < DBP * PROJ; i += 512) {
                int b = i / PROJ, p = i % PROJ;
                int bglob = bg * DBP + b;
                inp0[b][p]      = hs[(size_t)bglob * PROJ + p];
                inp0[b][48 + p] = xin[(size_t)bglob * INF * SEQ + (size_t)p * SEQ + (SEQ - 1)];
                h1b[b][p]       = hs[(size_t)(BATCH + bglob) * PROJ + p];
            }
            if (tid < DBP * OUTF) {
                int b = tid >> 4, f = tid & 15;
                inp0[b][96 + f] = xdec[(size_t)(bg * DBP + b) * (OUTF * FUT) + (size_t)f * FUT];
            }
        } else {
            if (tid < 192) {
                int b = tid / 12, p = (tid % 12) * 4;
                int bglob = bg * DBP + b;
                f32x4 s = gsum8(ppaR + (size_t)bglob * PROJ + p, PSTR);
                *reinterpret_cast<f32x4*>(&inp0[b][p]) = s;
            } else if (tid < 384) {
                int idx = tid - 192;
                int b = idx / 12, p = (idx % 12) * 4;
                int bglob = bg * DBP + b;
                f32x4 s = gsum8(ppbR + (size_t)bglob * PROJ + p, PSTR);
                *reinterpret_cast<f32x4*>(&inp0[b][48 + p]) = s;
                *reinterpret_cast<f32x4*>(&h1b[b][p]) = s;
                if (rg == 0)
                    *reinterpret_cast<f32x4*>(&PRED[((size_t)(t - 1) * BATCH + bglob) * PROJ + p]) = s;
            } else {
                #pragma unroll
                for (int rep = 0; rep < 2; ++rep) {
                    int i2 = (tid - 384) + rep * 128;
                    int b = i2 >> 4, f = i2 & 15;
                    inp0[b][96 + f] = xdec[(size_t)(bg * DBP + b) * (OUTF * FUT) + (size_t)f * FUT + t];
                }
            }
        }
        __syncthreads();

        // ---- L0 gates: 2 passes x 128 rows, 28 streamed weights ----
        #pragma unroll
        for (int p = 0; p < 2; ++p) {
            int rid = p * 128 + rhalf;
            int g = rid >> 6, u = rid & 63;
            int grow = g * HID + rg * DUP + u;
            float wv[28];
            #pragma unroll
            for (int kk = 0; kk < 28; ++kk) {
                int k = kq * 28 + kk;
                wv[kk] = (k < 48) ? Whh0[(size_t)grow * 48 + k]
                                  : Wih0[(size_t)grow * 64 + (k - 48)];
            }
            float acc[DBP];
            #pragma unroll
            for (int b = 0; b < DBP; ++b) acc[b] = 0.f;
            const float* srcA = &inp0[0][0] + kq * 28;
            #pragma unroll
            for (int i4 = 0; i4 < 7; ++i4) {
                float w0 = wv[i4*4], w1 = wv[i4*4+1], w2 = wv[i4*4+2], w3 = wv[i4*4+3];
                #pragma unroll
                for (int b = 0; b < DBP; ++b) {
                    float4 xv = *reinterpret_cast<const float4*>(&srcA[b * 120 + i4 * 4]);
                    acc[b] += w0*xv.x + w1*xv.y + w2*xv.z + w3*xv.w;
                }
            }
            #pragma unroll
            for (int b = 0; b < DBP; ++b) {
                acc[b] += __shfl_xor(acc[b], 1, 64);
                acc[b] += __shfl_xor(acc[b], 2, 64);
            }
            if (kq == 0) {
                #pragma unroll
                for (int b = 0; b < DBP; ++b) xch[g][u][b] = acc[b];
            }
        }
        __syncthreads();
        #pragma unroll
        for (int hh = 0; hh < 2; ++hh) {
            int b = b2 + 8 * hh;
            float gi = xch[0][u2][b] + bs0[0];
            float gf = xch[1][u2][b] + bs0[1];
            float gc = xch[2][u2][b] + bs0[2];
            float go = xch[3][u2][b] + bs0[3];
            float si = fsigmoid(gi), sf = fsigmoid(gf), so = fsigmoid(go), tg = ftanh(gc);
            c0[hh] = sf * c0[hh] + si * tg;
            htl[b][u2] = so * ftanh(c0[hh]);
        }
        __syncthreads();
        if (lane < PROJ) {
            #pragma unroll
            for (int bb = 0; bb < 2; ++bb) {
                int b = 2 * w + bb;
                float s = 0.f;
                #pragma unroll
                for (int u4 = 0; u4 < 16; ++u4) {
                    float4 hv = *reinterpret_cast<const float4*>(&htl[b][u4 * 4]);
                    s += wslT0[u4*4+0][lane]*hv.x + wslT0[u4*4+1][lane]*hv.y
                       + wslT0[u4*4+2][lane]*hv.z + wslT0[u4*4+3][lane]*hv.w;
                }
                gstore(&ppaW[(size_t)rg * PSTR + (size_t)(bg * DBP + b) * PROJ + lane], s);
            }
        }
        phase += 1;
        bsync(ctr, phase * DRG, tid);

        // ================= PHASE B: gather h0' + L1 + proj1 =================
        if (tid < 192) {
            int b = tid / 12, p = (tid % 12) * 4;
            f32x4 s = gsum8(ppaW + (size_t)(bg * DBP + b) * PROJ + p, PSTR);
            *reinterpret_cast<f32x4*>(&h0n[b][p]) = s;
        }
        __syncthreads();

        #pragma unroll
        for (int p = 0; p < 2; ++p) {
            int rid = p * 128 + rhalf;
            int g = rid >> 6, u = rid & 63;
            int grow = g * HID + rg * DUP + u;
            float wv[24];
            #pragma unroll
            for (int kk = 0; kk < 24; ++kk) {
                int k = kq * 24 + kk;
                wv[kk] = (k < 48) ? Whh1[(size_t)grow * 48 + k]
                                  : Wih1[(size_t)grow * 48 + (k - 48)];
            }
            const float* srcB = (kq < 2) ? (&h1b[0][0] + kq * 24)
                                         : (&h0n[0][0] + (kq - 2) * 24);
            float acc[DBP];
            #pragma unroll
            for (int b = 0; b < DBP; ++b) acc[b] = 0.f;
            #pragma unroll
            for (int i4 = 0; i4 < 6; ++i4) {
                float w0 = wv[i4*4], w1 = wv[i4*4+1], w2 = wv[i4*4+2], w3 = wv[i4*4+3];
                #pragma unroll
                for (int b = 0; b < DBP; ++b) {
                    float4 xv = *reinterpret_cast<const float4*>(&srcB[b * 52 + i4 * 4]);
                    acc[b] += w0*xv.x + w1*xv.y + w2*xv.z + w3*xv.w;
                }
            }
            #pragma unroll
            for (int b = 0; b < DBP; ++b) {
                acc[b] += __shfl_xor(acc[b], 1, 64);
                acc[b] += __shfl_xor(acc[b], 2, 64);
            }
            if (kq == 0) {
                #pragma unroll
                for (int b = 0; b < DBP; ++b) xch[g][u][b] = acc[b];
            }
        }
        __syncthreads();
        #pragma unroll
        for (int hh = 0; hh < 2; ++hh) {
            int b = b2 + 8 * hh;
            float gi = xch[0][u2][b] + bs1[0];
            float gf = xch[1][u2][b] + bs1[1];
            float gc = xch[2][u2][b] + bs1[2];
            float go = xch[3][u2][b] + bs1[3];
            float si = fsigmoid(gi), sf = fsigmoid(gf), so = fsigmoid(go), tg = ftanh(gc);
            c1[hh] = sf * c1[hh] + si * tg;
            htl[b][u2] = so * ftanh(c1[hh]);
        }
        __syncthreads();
        if (lane < PROJ) {
            #pragma unroll
            for (int bb = 0; bb < 2; ++bb) {
                int b = 2 * w + bb;
                float s = 0.f;
                #pragma unroll
                for (int u4 = 0; u4 < 16; ++u4) {
                    float4 hv = *reinterpret_cast<const float4*>(&htl[b][u4 * 4]);
                    s += wslT1[u4*4+0][lane]*hv.x + wslT1[u4*4+1][lane]*hv.y
                       + wslT1[u4*4+2][lane]*hv.z + wslT1[u4*4+3][lane]*hv.w;
                }
                gstore(&ppbW[(size_t)rg * PSTR + (size_t)(bg * DBP + b) * PROJ + lane], s);
            }
        }
        phase += 1;
        bsync(ctr, phase * DRG, tid);
    }

    // epilogue: PRED[FUT-1]
    if (tid < 2 * PROJ) {
        int bb = tid / PROJ, p = tid % PROJ;
        int bglob = bg * DBP + 2 * rg + bb;
        const float* ppbF = PPb + (size_t)((FUT - 1) & 1) * DPP;
        float s = 0.f;
        #pragma unroll
        for (int rr = 0; rr < DRG; ++rr)
            s += gload(&ppbF[(size_t)rr * PSTR + (size_t)bglob * PROJ + p]);
        PRED[((size_t)(FUT - 1) * BATCH + bglob) * PROJ + p] = s;
    }
}

// ---------------- basis contractions ----------------
__global__ void k_final(const float* __restrict__ theta, const float* __restrict__ H1,
                        const float* __restrict__ PRED, float* __restrict__ out)
{
    int b = blockIdx.x;
    __shared__ float th[2 * PROJ];
    if (threadIdx.x < 2 * PROJ) th[threadIdx.x] = theta[(size_t)b * 2 * PROJ + threadIdx.x];
    __syncthreads();
    for (int t = threadIdx.x; t < SEQ; t += 256) {
        float s = 0.f;
        #pragma unroll
        for (int p = 0; p < PROJ; ++p) s += th[PROJ + p] * H1[((size_t)t * BATCH + b) * PROJ + p];
        out[(size_t)b * SEQ + t] = s;
    }
    for (int t = threadIdx.x; t < FUT; t += 256) {
        float s = 0.f;
        #pragma unroll
        for (int p = 0; p < PROJ; ++p) s += th[p] * PRED[((size_t)t * BATCH + b) * PROJ + p];
        out[(size_t)BATCH * SEQ + (size_t)b * FUT + t] = s;
    }
}

extern "C" void kernel_launch(void* const* d_in, const int* in_sizes, int n_in,
                              void* d_out, int out_size, void* d_ws, size_t ws_size,
                              hipStream_t stream)
{
    (void)in_sizes; (void)n_in; (void)out_size; (void)ws_size;
    const float* theta = (const float*)d_in[0];
    const float* xin   = (const float*)d_in[1];
    const float* xdec  = (const float*)d_in[2];
    const float* eW0i = (const float*)d_in[3];
    const float* eW0h = (const float*)d_in[4];
    const float* eb0i = (const float*)d_in[5];
    const float* eb0h = (const float*)d_in[6];
    const float* eW0r = (const float*)d_in[7];
    const float* eW1i = (const float*)d_in[8];
    const float* eW1h = (const float*)d_in[9];
    const float* eb1i = (const float*)d_in[10];
    const float* eb1h = (const float*)d_in[11];
    const float* eW1r = (const float*)d_in[12];
    const float* dW0i = (const float*)d_in[13];
    const float* dW0h = (const float*)d_in[14];
    const float* db0i = (const float*)d_in[15];
    const float* db0h = (const float*)d_in[16];
    const float* dW0r = (const float*)d_in[17];
    const float* dW1i = (const float*)d_in[18];
    const float* dW1h = (const float*)d_in[19];
    const float* db1i = (const float*)d_in[20];
    const float* db1h = (const float*)d_in[21];
    const float* dW1r = (const float*)d_in[22];

    float* ws = (float*)d_ws;
    size_t off = 0;
    float* H0x  = ws + off; off += (size_t)SEQ * BATCH * PROJ;
    float* H1   = ws + off; off += (size_t)SEQ * BATCH * PROJ;
    float* PRED = ws + off; off += (size_t)FUT * BATCH * PROJ;
    float* hs   = ws + off; off += (size_t)2 * BATCH * PROJ;
    float* cs   = ws + off; off += (size_t)2 * BATCH * HID;
    float* WT0  = ws + off; off += (size_t)INF * G4;
    float* WT1  = ws + off; off += (size_t)PROJ * G4;
    const size_t DPP = (size_t)DRG * BATCH * PROJ;
    float* PPa  = ws + off; off += 2 * DPP;
    float* PPb  = ws + off; off += 2 * DPP;
    off = (off + 63) & ~(size_t)63;
    unsigned* eflags = (unsigned*)(ws + off); off += BATCH * 16;
    unsigned* bar    = (unsigned*)(ws + off); off += DBG * 64;

    hipMemsetAsync(eflags, 0, (BATCH * 16 + DBG * 64) * sizeof(unsigned), stream);
    k_wtrans<<<dim3(G4 / 32, 2), dim3(32, 8), 0, stream>>>(eW0i, WT0, G4, INF);
    k_wtrans<<<dim3(G4 / 32, 2), dim3(32, 8), 0, stream>>>(eW1i, WT1, G4, PROJ);
    k_enc<<<2 * BATCH, 512, 0, stream>>>(xin,
                                         WT0, eW0h, eb0i, eb0h, eW0r,
                                         WT1, eW1h, eb1i, eb1h, eW1r,
                                         H0x, H1, hs, cs, eflags);
    k_decP<<<DRG * DBG, 512, 0, stream>>>(xdec, dW0i, dW0h, db0i, db0h, dW0r,
                                          dW1i, dW1h, db1i, db1h, dW1r,
                                          hs, cs, xin, PPa, PPb, PRED, bar);
    k_final<<<BATCH, 256, 0, stream>>>(theta, H1, PRED, (float*)d_out);
}